// Round 4
// baseline (20908.195 us; speedup 1.0000x reference)
//
#include <hip/hip_runtime.h>
#include <hip/hip_fp16.h>

#define BB   64
#define TDEC 400
#define TENC 512
#define DD   256
#define PRE  128
#define NOUT 400
#define G3   768

typedef _Float16 h2_t __attribute__((ext_vector_type(2)));

#define AT_STORE(p, v) __hip_atomic_store((p), (v), __ATOMIC_RELAXED, __HIP_MEMORY_SCOPE_AGENT)
#define AT_LOAD(p)     __hip_atomic_load((p),        __ATOMIC_RELAXED, __HIP_MEMORY_SCOPE_AGENT)

// ---------------- fast math ----------------
__device__ __forceinline__ float fsig(float x) {
    return __builtin_amdgcn_rcpf(1.0f + __expf(-x));
}
__device__ __forceinline__ float ftanh(float x) {
    float t = __expf(2.0f * x);
    return 1.0f - 2.0f * __builtin_amdgcn_rcpf(t + 1.0f);
}
// 8-term fp16 x fp16 -> fp32 dot from two 16B packets
__device__ __forceinline__ float dot8(float4 w, float4 x, float acc) {
    union { float4 f; h2_t h[4]; } uw, ux;
    uw.f = w; ux.f = x;
#if __has_builtin(__builtin_amdgcn_fdot2)
    #pragma unroll
    for (int k = 0; k < 4; k++)
        acc = __builtin_amdgcn_fdot2(uw.h[k], ux.h[k], acc, false);
#else
    #pragma unroll
    for (int k = 0; k < 4; k++) {
        acc = fmaf((float)uw.h[k].x, (float)ux.h[k].x, acc);
        acc = fmaf((float)uw.h[k].y, (float)ux.h[k].y, acc);
    }
#endif
    return acc;
}

// ---------------- prenet ----------------
__global__ __launch_bounds__(256) void prenet_kernel(
    const float* __restrict__ x, const float* __restrict__ W1, const float* __restrict__ b1,
    const float* __restrict__ W2, const float* __restrict__ b2, __half* __restrict__ p_h)
{
    __shared__ __align__(16) float xs[8][NOUT];
    __shared__ __align__(16) float hs[8][DD];
    const int row0 = blockIdx.x * 8;
    const int tid = threadIdx.x;
    for (int idx = tid; idx < 8 * NOUT; idx += 256) {
        int m = idx / NOUT, i = idx - m * NOUT;
        xs[m][i] = x[(size_t)(row0 + m) * NOUT + i];
    }
    __syncthreads();
    {
        const int j = tid;
        float acc[8];
        float bj = b1[j];
        #pragma unroll
        for (int m = 0; m < 8; m++) acc[m] = bj;
        #pragma unroll 4
        for (int i = 0; i < NOUT; i++) {
            float w = W1[i * DD + j];
            #pragma unroll
            for (int m = 0; m < 8; m++) acc[m] = fmaf(xs[m][i], w, acc[m]);
        }
        #pragma unroll
        for (int m = 0; m < 8; m++) hs[m][j] = fmaxf(acc[m], 0.0f);
    }
    __syncthreads();
    if (tid < PRE) {
        const int j = tid;
        float acc[8];
        float bj = b2[j];
        #pragma unroll
        for (int m = 0; m < 8; m++) acc[m] = bj;
        #pragma unroll 4
        for (int i = 0; i < DD; i++) {
            float w = W2[i * PRE + j];
            #pragma unroll
            for (int m = 0; m < 8; m++) acc[m] = fmaf(hs[m][i], w, acc[m]);
        }
        #pragma unroll
        for (int m = 0; m < 8; m++)
            p_h[(size_t)(row0 + m) * PRE + j] = __float2half(fmaxf(acc[m], 0.0f));
    }
}

// ---------------- keys = fp16(memory @ Wm) ----------------
__global__ __launch_bounds__(256) void keys_kernel(
    const float* __restrict__ mem, const float* __restrict__ Wm, __half* __restrict__ keys_h)
{
    __shared__ __align__(16) float xs[8][DD];
    const int row0 = blockIdx.x * 8;
    const int tid = threadIdx.x;
    for (int idx = tid; idx < 8 * DD; idx += 256) {
        int m = idx >> 8, i = idx & 255;
        xs[m][i] = mem[(size_t)(row0 + m) * DD + i];
    }
    __syncthreads();
    const int j = tid;
    float acc[8] = {0.f,0.f,0.f,0.f,0.f,0.f,0.f,0.f};
    #pragma unroll 4
    for (int i = 0; i < DD; i++) {
        float w = Wm[i * DD + j];
        #pragma unroll
        for (int m = 0; m < 8; m++) acc[m] = fmaf(xs[m][i], w, acc[m]);
    }
    #pragma unroll
    for (int m = 0; m < 8; m++) keys_h[(size_t)(row0 + m) * DD + j] = __float2half(acc[m]);
}

// ---------------- generic 8-row pack: dst[(i8*C + j)*8 + k] = fp16 src[8*i8+k][j] ----------------
__global__ __launch_bounds__(256) void pack_w_kernel(
    const float* __restrict__ src, __half* __restrict__ dst, int R, int C)
{
    int flat = blockIdx.x * 256 + threadIdx.x;
    if (flat < R * C) {
        int k = flat & 7;
        int t2 = flat >> 3;
        int j = t2 % C;
        int i8 = t2 / C;
        dst[flat] = __float2half(src[(size_t)(8 * i8 + k) * C + j]);
    }
}

// ---- gate pack for role s: cols c<384 map to gate G = (c/128)*256 + s*128 + c%128 ----
__global__ __launch_bounds__(256) void pack_gate_kernel(
    const float* __restrict__ src, __half* __restrict__ dst, int K, int s)
{
    int flat = blockIdx.x * 256 + threadIdx.x;
    if (flat < K * 384) {
        int k = flat & 7;
        int r2 = flat >> 3;
        int c = r2 % 384;
        int i8 = r2 / 384;
        int G = (c >> 7) * 256 + s * 128 + (c & 127);
        dst[flat] = __float2half(src[(size_t)(8 * i8 + k) * G3 + G]);
    }
}

// ---- Wa pack role s: dst[(i8*128 + j)*8 + k] = Wa[8i8+k][s*128+j], i8<64 ----
__global__ __launch_bounds__(256) void pack_wa_kernel(
    const float* __restrict__ src, __half* __restrict__ dst, int s)
{
    int flat = blockIdx.x * 256 + threadIdx.x;
    if (flat < 512 * 128) {
        int k = flat & 7;
        int r2 = flat >> 3;
        int j = r2 & 127;
        int i8 = r2 >> 7;
        dst[flat] = __float2half(src[(size_t)(8 * i8 + k) * 256 + s * 128 + j]);
    }
}

// ---- mem pack: dst[b*65536 + e2*256 + d] = {mem[b][2e2][d], mem[b][2e2+1][d]} ----
__global__ __launch_bounds__(256) void pack_mem_kernel(
    const float* __restrict__ mem, __half2* __restrict__ dst)
{
    int flat = blockIdx.x * 256 + threadIdx.x;
    if (flat < BB * 256 * 256) {
        int d  = flat & 255;
        int e2 = (flat >> 8) & 255;
        int b  = flat >> 16;
        const float* base = mem + ((size_t)b * TENC + 2 * e2) * DD + d;
        dst[flat] = __floats2half2_rn(base[0], base[DD]);
    }
}

// ---------------- y = ahist(fp16) @ Wo + bo ----------------
__global__ __launch_bounds__(448) void out_kernel(
    const __half* __restrict__ ah, const float* __restrict__ Wo, const float* __restrict__ bo,
    float* __restrict__ y)
{
    __shared__ __align__(16) float xs[8][DD];
    const int row0 = blockIdx.x * 8;
    const int tid = threadIdx.x;
    for (int idx = tid; idx < 8 * DD; idx += 448) {
        int m = idx >> 8, i = idx & 255;
        xs[m][i] = __half2float(ah[(size_t)(row0 + m) * DD + i]);
    }
    __syncthreads();
    if (tid < NOUT) {
        const int j = tid;
        float acc[8];
        float bj = bo[j];
        #pragma unroll
        for (int m = 0; m < 8; m++) acc[m] = bj;
        #pragma unroll 4
        for (int i = 0; i < DD; i++) {
            float w = Wo[i * NOUT + j];
            #pragma unroll
            for (int m = 0; m < 8; m++) acc[m] = fmaf(xs[m][i], w, acc[m]);
        }
        #pragma unroll
        for (int m = 0; m < 8; m++) y[(size_t)(row0 + m) * NOUT + j] = acc[m];
    }
}

// ---- pairwise handshake: publish own flag, wait partner's (monotonic tags, poison-safe) ----
__device__ __forceinline__ void pair_sync(int* fo, int* fp, int ph, int tag) {
    __syncthreads();   // drains vmcnt: all data stores of this block globally visible
    if (threadIdx.x == 0) {
        __hip_atomic_store(fo + ph, tag, __ATOMIC_RELEASE, __HIP_MEMORY_SCOPE_AGENT);
        while (__hip_atomic_load(fp + ph, __ATOMIC_ACQUIRE, __HIP_MEMORY_SCOPE_AGENT) < tag)
            __builtin_amdgcn_s_sleep(1);
    }
    __syncthreads();
}

// ---------------- decoder: 128 blocks = 64 batch x 2 roles, 768 threads ----------------
// Pair (b, b+64) lands on the same XCD under the %8 round-robin heuristic (perf only;
// correctness uses agent-scope atomics, placement-independent).
__global__ __launch_bounds__(768) void decoder_kernel(
    const __half* __restrict__ p_h,  const __half* __restrict__ keys_h,
    const __half2* __restrict__ mem_p,
    const __half* __restrict__ k0p,  const __half* __restrict__ r0p,
    const __half* __restrict__ k1p,  const __half* __restrict__ r1p,
    const __half* __restrict__ Wqp,  const __half* __restrict__ Wap,
    const float* __restrict__ bi0, const float* __restrict__ br0,
    const float* __restrict__ bi1, const float* __restrict__ br1,
    const float* __restrict__ v,
    float* __restrict__ xch, int* __restrict__ flags,
    __half* __restrict__ ahist)
{
    __shared__ __align__(16) __half xa[384];            // [p_t | att] fp16, full
    __shared__ __align__(16) __half h0s[DD], h1s[DD];   // full fp16 state
    __shared__ __align__(16) float  h0f[128], h1f[128]; // own-half fp32 carry
    __shared__ __align__(16) __half qvh[2 * DD], vh[DD];
    __shared__ __align__(16) __half ins[2 * DD];        // [h1 | ctx]
    __shared__ __align__(16) float  gxp[384 * 2], ghp[384 * 2];
    __shared__ __align__(16) float  gx[384], gh[384];
    __shared__ __align__(16) float  sc3p[256 * 4];
    __shared__ __align__(16) float  we[256];
    __shared__ __align__(16) float  nump[256 * 2], numo[256];
    __shared__ __align__(16) float  attp[128 * 4];
    __shared__ __align__(16) float  b0i_l[384], b0r_l[384], b1i_l[384], b1r_l[384];
    __shared__ float redd[4];
    __shared__ float sdenl[2];

    const int tid = threadIdx.x;
    const int b = blockIdx.x & 63;
    const int s = blockIdx.x >> 6;

    if (tid < 384) {
        int c = tid;
        int G = (c >> 7) * 256 + s * 128 + (c & 127);
        b0i_l[c] = bi0[G]; b0r_l[c] = br0[G]; b1i_l[c] = bi1[G]; b1r_l[c] = br1[G];
    }
    if (tid < DD) {
        vh[tid] = __float2half(v[tid]);
        h0s[tid] = __float2half(0.0f); h1s[tid] = __float2half(0.0f);
        xa[PRE + tid] = __float2half(0.0f);
    }
    if (tid < 128) { h0f[tid] = 0.0f; h1f[tid] = 0.0f; }
    __syncthreads();

    // role-sliced weight bases (halves)
    const float4* k0ps = (const float4*)(k0p + (size_t)s * 48 * 384 * 8);
    const float4* r0ps = (const float4*)(r0p + (size_t)s * 32 * 384 * 8);
    const float4* k1ps = (const float4*)(k1p + (size_t)s * 32 * 384 * 8);
    const float4* r1ps = (const float4*)(r1p + (size_t)s * 32 * 384 * 8);
    const float4* Wqp4 = (const float4*)Wqp;
    const float4* Waps = (const float4*)(Wap + (size_t)s * 64 * 128 * 8);

    const __half*  keybs = keys_h + ((size_t)b * TENC + s * 256) * DD;
    const __half2* membs = mem_p + (size_t)b * 256 * DD + (size_t)(s * 128) * DD;
    const float4*  pb4   = (const float4*)(p_h + (size_t)b * TDEC * PRE);

    float* xo  = xch + (size_t)((b << 1) + s) * 1024;        // own exchange region
    float* xp_ = xch + (size_t)((b << 1) + (1 - s)) * 1024;  // partner region
    int*   fo  = flags + ((b << 1) + s) * 32;
    int*   fp  = flags + ((b << 1) + (1 - s)) * 32;

    #pragma unroll 1
    for (int t = 0; t < TDEC; t++) {
        const int tag = t + 1;
        // stage p_t (128 halves = 16 float4)
        if (tid < 16) ((float4*)xa)[tid] = pb4[t * 16 + tid];
        __syncthreads();

        // ---- GRU0: 384 local gate cols x (48 + 32) i8, split K in halves ----
        {
            int hf = (tid >= 384) ? 1 : 0;
            int c = tid - (hf << 8) - (hf << 7);   // tid - 384*hf
            const float4* xp4 = (const float4*)xa;
            float acc = 0.0f;
            int i8b = hf * 24;
            #pragma unroll 8
            for (int i = 0; i < 24; i++) acc = dot8(k0ps[(i8b + i) * 384 + c], xp4[i8b + i], acc);
            gxp[c * 2 + hf] = acc;
            const float4* hp4 = (const float4*)h0s;
            float acc2 = 0.0f;
            int j8b = hf * 16;
            #pragma unroll 8
            for (int i = 0; i < 16; i++) acc2 = dot8(r0ps[(j8b + i) * 384 + c], hp4[j8b + i], acc2);
            ghp[c * 2 + hf] = acc2;
        }
        __syncthreads();
        if (tid < 384) {
            gx[tid] = gxp[tid * 2] + gxp[tid * 2 + 1] + b0i_l[tid];
            gh[tid] = ghp[tid * 2] + ghp[tid * 2 + 1] + b0r_l[tid];
        }
        __syncthreads();
        if (tid < 128) {
            float z = fsig(gx[tid] + gh[tid]);
            float r = fsig(gx[128 + tid] + gh[128 + tid]);
            float cand = ftanh(gx[256 + tid] + r * gh[256 + tid]);
            float hn = z * h0f[tid] + (1.0f - z) * cand;
            h0f[tid] = hn;
            h0s[s * 128 + tid] = __float2half(hn);
            AT_STORE(xo + tid, hn);
        }
        pair_sync(fo, fp, 0, tag);
        if (tid < 128) h0s[(1 - s) * 128 + tid] = __float2half(AT_LOAD(xp_ + tid));
        __syncthreads();

        // ---- GRU1: 384 local gate cols x (32 + 32) i8 ----
        {
            int hf = (tid >= 384) ? 1 : 0;
            int c = tid - (hf << 8) - (hf << 7);
            const float4* hp0 = (const float4*)h0s;
            const float4* hp1 = (const float4*)h1s;
            float acc = 0.0f, acc2 = 0.0f;
            int i8b = hf * 16;
            #pragma unroll 8
            for (int i = 0; i < 16; i++) {
                acc  = dot8(k1ps[(i8b + i) * 384 + c], hp0[i8b + i], acc);
                acc2 = dot8(r1ps[(i8b + i) * 384 + c], hp1[i8b + i], acc2);
            }
            gxp[c * 2 + hf] = acc;
            ghp[c * 2 + hf] = acc2;
        }
        __syncthreads();
        if (tid < 384) {
            gx[tid] = gxp[tid * 2] + gxp[tid * 2 + 1] + b1i_l[tid];
            gh[tid] = ghp[tid * 2] + ghp[tid * 2 + 1] + b1r_l[tid];
        }
        __syncthreads();
        if (tid < 128) {
            float z = fsig(gx[tid] + gh[tid]);
            float r = fsig(gx[128 + tid] + gh[128 + tid]);
            float cand = ftanh(gx[256 + tid] + r * gh[256 + tid]);
            float hn = z * h1f[tid] + (1.0f - z) * cand;
            h1f[tid] = hn;
            h1s[s * 128 + tid] = __float2half(hn);
            AT_STORE(xo + 128 + tid, hn);
        }
        pair_sync(fo, fp, 1, tag);
        if (tid < 128) h1s[(1 - s) * 128 + tid] = __float2half(AT_LOAD(xp_ + 128 + tid));
        __syncthreads();

        // ---- q = h1 @ Wq (full, duplicated across the pair to skip a sync) ----
        if (tid < 512) {
            int hf = tid >> 8, c = tid & 255;
            const float4* hp4 = (const float4*)h1s;
            float acc = 0.0f;
            int i8b = hf * 16;
            #pragma unroll 8
            for (int i = 0; i < 16; i++) acc = dot8(Wqp4[(i8b + i) * 256 + c], hp4[i8b + i], acc);
            gxp[c * 2 + hf] = acc;
        }
        __syncthreads();
        if (tid < 256) {
            float qf = gxp[tid * 2] + gxp[tid * 2 + 1];
            qvh[2 * tid] = __float2half(qf);
            qvh[2 * tid + 1] = vh[tid];
        }
        __syncthreads();

        // ---- scores for e-half (256 rows), d split in thirds across 768 threads ----
        {
            int th = tid >> 8, e = tid & 255;
            const float4* kp = (const float4*)(keybs + (size_t)e * DD);
            const float4* qp = (const float4*)qvh;
            float ssum = 0.0f;
            int i8b = th * 11;
            int cnt = (th == 2) ? 10 : 11;
            for (int ii = 0; ii < cnt; ii++) {
                int i8 = i8b + ii;
                union { float4 f; h2_t h[4]; } uk, u0, u1;
                uk.f = kp[i8]; u0.f = qp[2 * i8]; u1.f = qp[2 * i8 + 1];
                ssum = fmaf((float)u0.h[0].y, ftanh((float)uk.h[0].x + (float)u0.h[0].x), ssum);
                ssum = fmaf((float)u0.h[1].y, ftanh((float)uk.h[0].y + (float)u0.h[1].x), ssum);
                ssum = fmaf((float)u0.h[2].y, ftanh((float)uk.h[1].x + (float)u0.h[2].x), ssum);
                ssum = fmaf((float)u0.h[3].y, ftanh((float)uk.h[1].y + (float)u0.h[3].x), ssum);
                ssum = fmaf((float)u1.h[0].y, ftanh((float)uk.h[2].x + (float)u1.h[0].x), ssum);
                ssum = fmaf((float)u1.h[1].y, ftanh((float)uk.h[2].y + (float)u1.h[1].x), ssum);
                ssum = fmaf((float)u1.h[2].y, ftanh((float)uk.h[3].x + (float)u1.h[2].x), ssum);
                ssum = fmaf((float)u1.h[3].y, ftanh((float)uk.h[3].y + (float)u1.h[3].x), ssum);
            }
            sc3p[e * 4 + th] = ssum;
        }
        __syncthreads();
        {
            float wv = 0.0f;
            if (tid < 256) {
                float sv = sc3p[tid * 4] + sc3p[tid * 4 + 1] + sc3p[tid * 4 + 2];
                wv = __expf(sv);
                we[tid] = wv;
            }
            float dsum = wv;
            #pragma unroll
            for (int off = 32; off; off >>= 1) dsum += __shfl_down(dsum, off);
            if (tid < 256 && (tid & 63) == 0) redd[tid >> 6] = dsum;
        }
        __syncthreads();

        // ---- partial num[d] over own e-half ----
        if (tid < 512) {
            int hf = tid >> 8, d = tid & 255;
            const __half2* mp = membs + (size_t)(hf * 64) * DD + d;
            float acc = 0.0f;
            #pragma unroll 4
            for (int i = 0; i < 64; i++) {
                float2 f = __half22float2(mp[(size_t)i * DD]);
                int el = (hf * 64 + i) * 2;
                acc = fmaf(f.x, we[el], acc);
                acc = fmaf(f.y, we[el + 1], acc);
            }
            nump[d * 2 + hf] = acc;
        }
        __syncthreads();
        if (tid < 256) {
            float nm = nump[tid * 2] + nump[tid * 2 + 1];
            numo[tid] = nm;
            AT_STORE(xo + 256 + tid, nm);
        }
        if (tid == 0) {
            float den = redd[0] + redd[1] + redd[2] + redd[3];
            sdenl[0] = den;
            AT_STORE(xo + 512, den);
        }
        pair_sync(fo, fp, 2, tag);
        if (tid < 256) gx[tid] = numo[tid] + AT_LOAD(xp_ + 256 + tid);
        if (tid == 0) sdenl[1] = AT_LOAD(xp_ + 512);
        __syncthreads();
        if (tid < 256) {
            float invS = __builtin_amdgcn_rcpf(sdenl[0] + sdenl[1]);
            ins[tid] = h1s[tid];
            ins[256 + tid] = __float2half(gx[tid] * invS);
        }
        __syncthreads();

        // ---- attn own j-half: [h1|ctx](512) @ Wa[:, j-half] ----
        if (tid < 512) {
            int q4 = tid >> 7, j = tid & 127;
            const float4* ip4 = (const float4*)ins;
            float acc = 0.0f;
            int i8b = q4 * 16;
            #pragma unroll 8
            for (int i = 0; i < 16; i++) acc = dot8(Waps[(i8b + i) * 128 + j], ip4[i8b + i], acc);
            attp[j * 4 + q4] = acc;
        }
        __syncthreads();
        if (tid < 128) {
            float av = attp[tid * 4] + attp[tid * 4 + 1] + attp[tid * 4 + 2] + attp[tid * 4 + 3];
            int jg = s * 128 + tid;
            __half ah = __float2half(av);
            xa[PRE + jg] = ah;
            ahist[((size_t)b * TDEC + t) * DD + jg] = ah;
            AT_STORE(xo + 640 + tid, av);
        }
        pair_sync(fo, fp, 3, tag);
        if (tid < 128)
            xa[PRE + (1 - s) * 128 + tid] = __float2half(AT_LOAD(xp_ + 640 + tid));
        // loop-top __syncthreads (after p staging) publishes xa block-wide
    }
}

extern "C" void kernel_launch(void* const* d_in, const int* in_sizes, int n_in,
                              void* d_out, int out_size, void* d_ws, size_t ws_size,
                              hipStream_t stream)
{
    const float* dec    = (const float*)d_in[0];
    const float* memory = (const float*)d_in[1];
    const float* W1  = (const float*)d_in[2];
    const float* b1  = (const float*)d_in[3];
    const float* W2  = (const float*)d_in[4];
    const float* b2  = (const float*)d_in[5];
    const float* k0  = (const float*)d_in[6];
    const float* r0  = (const float*)d_in[7];
    const float* bi0 = (const float*)d_in[8];
    const float* br0 = (const float*)d_in[9];
    const float* k1  = (const float*)d_in[10];
    const float* r1  = (const float*)d_in[11];
    const float* bi1 = (const float*)d_in[12];
    const float* br1 = (const float*)d_in[13];
    const float* Wq  = (const float*)d_in[14];
    const float* Wm  = (const float*)d_in[15];
    const float* v   = (const float*)d_in[16];
    const float* Wa  = (const float*)d_in[17];
    const float* Wo  = (const float*)d_in[18];
    const float* bo  = (const float*)d_in[19];
    float* out = (float*)d_out;
    (void)ws_size; (void)in_sizes; (void)n_in; (void)out_size;

    // ---- workspace layout ----
    char* w = (char*)d_ws;
    size_t off = 0;
    __half*  p_h    = (__half*)(w + off);  off += (size_t)BB * TDEC * PRE * 2;       // 6.55 MB
    __half*  keys_h = (__half*)(w + off);  off += (size_t)BB * TENC * DD * 2;        // 16.8 MB
    __half2* mem_p  = (__half2*)(w + off); off += (size_t)BB * TENC * DD * 2;        // 16.8 MB
    __half*  k0p    = (__half*)(w + off);  off += (size_t)2 * 48 * 384 * 8 * 2;      // 590 KB
    __half*  r0p    = (__half*)(w + off);  off += (size_t)2 * 32 * 384 * 8 * 2;      // 393 KB
    __half*  k1p    = (__half*)(w + off);  off += (size_t)2 * 32 * 384 * 8 * 2;
    __half*  r1p    = (__half*)(w + off);  off += (size_t)2 * 32 * 384 * 8 * 2;
    __half*  Wqp    = (__half*)(w + off);  off += (size_t)DD * DD * 2;               // 131 KB
    __half*  Wap    = (__half*)(w + off);  off += (size_t)2 * 64 * 128 * 8 * 2;      // 262 KB
    float*   xch    = (float*)(w + off);   off += (size_t)128 * 1024 * 4;            // 524 KB
    int*     flags  = (int*)(w + off);     off += (size_t)128 * 32 * 4;              // 16 KB
    __half*  ahist  = (__half*)(w + off);  off += (size_t)BB * TDEC * DD * 2;        // 13.1 MB

    // precompute (parallel, outside the recurrence)
    prenet_kernel<<<BB * TDEC / 8, 256, 0, stream>>>(dec, W1, b1, W2, b2, p_h);
    keys_kernel<<<BB * TENC / 8, 256, 0, stream>>>(memory, Wm, keys_h);
    pack_mem_kernel<<<(BB * 256 * 256) / 256, 256, 0, stream>>>(memory, mem_p);
    for (int s = 0; s < 2; s++) {
        pack_gate_kernel<<<(384 * 384 + 255) / 256, 256, 0, stream>>>(
            k0, k0p + (size_t)s * 48 * 384 * 8, 384, s);
        pack_gate_kernel<<<(256 * 384 + 255) / 256, 256, 0, stream>>>(
            r0, r0p + (size_t)s * 32 * 384 * 8, 256, s);
        pack_gate_kernel<<<(256 * 384 + 255) / 256, 256, 0, stream>>>(
            k1, k1p + (size_t)s * 32 * 384 * 8, 256, s);
        pack_gate_kernel<<<(256 * 384 + 255) / 256, 256, 0, stream>>>(
            r1, r1p + (size_t)s * 32 * 384 * 8, 256, s);
        pack_wa_kernel<<<(512 * 128 + 255) / 256, 256, 0, stream>>>(
            Wa, Wap + (size_t)s * 64 * 128 * 8, s);
    }
    pack_w_kernel<<<(DD * DD + 255) / 256, 256, 0, stream>>>(Wq, Wqp, DD, DD);

    // the 400-step recurrence: 64 batch x 2 column-role blocks, pairwise handshakes
    decoder_kernel<<<128, 768, 0, stream>>>(p_h, keys_h, mem_p, k0p, r0p, k1p, r1p,
                                            Wqp, Wap, bi0, br0, bi1, br1, v,
                                            xch, flags, ahist);

    // output projection (outside the recurrence)
    out_kernel<<<BB * TDEC / 8, 448, 0, stream>>>(ahist, Wo, bo, out);
}